// Round 6
// baseline (588.560 us; speedup 1.0000x reference)
//
#include <hip/hip_runtime.h>
#include <math.h>
#include <stdint.h>

#define B_TOT 2048
#define SEQ   512
#define DIN   5
#define HID   64
#define EDIM  32
#define NEMB  64
#define BT    16
#define NBLK_STREAM 128
#define COMB  96
#define OUTC  (B_TOT*COMB)

typedef __attribute__((ext_vector_type(8))) _Float16 half8;  // 8 fp16 = 4 VGPRs
typedef __attribute__((ext_vector_type(4))) float float4v;

#if __has_builtin(__builtin_amdgcn_exp2f)
#define FEXP2(x) __builtin_amdgcn_exp2f(x)
#else
#define FEXP2(x) exp2f(x)
#endif
#if __has_builtin(__builtin_amdgcn_rcpf)
#define FRCP(x) __builtin_amdgcn_rcpf(x)
#else
#define FRCP(x) (1.0f/(x))
#endif

#define L2E  1.44269504089f
#define L2E2 2.88539008178f

// 7-trans LSTM cell (5 exp2 + 2 rcp) — exact algebra, NaN-free:
//   c' = (c*Dig + (1-eg)*Df) * rcp(Dig*Df),  Dig=(1+ei)(1+eg), Df=1+ef
//   h  = (1-ec) * rcp((1+eo)(1+ec)),  ec=e^-2c' (arg clamped at 126)
__device__ __forceinline__ float lstm_cell(float4v a, const float* bp, float& c){
  float ei = FEXP2(fmaf(a[0], -L2E,  bp[0]));
  float ef = FEXP2(fmaf(a[1], -L2E,  bp[1]));
  float eg = FEXP2(fmaf(a[2], -L2E2, bp[2]));
  float eo = FEXP2(fmaf(a[3], -L2E,  bp[3]));
  float Dig = (1.f + ei) * (1.f + eg);
  float Df  = 1.f + ef;
  float rD  = FRCP(Dig * Df);
  float t   = fmaf(-eg, Df, Df);            // Df*(1-eg)
  c = fmaf(c, Dig, t) * rD;
  float ec = FEXP2(fminf(-L2E2 * c, 126.f));
  return (1.f - ec) * FRCP((1.f + eo) * (1.f + ec));
}

#define MFMA16(a,b,c) __builtin_amdgcn_mfma_f32_16x16x32_f16((a),(b),(c),0,0,0)

// In-loop barrier: drain LDS writes only; global prefetch (vmcnt) stays in
// flight across the barrier; compiler's vmcnt wait at the use covers it.
#define LOOP_BARRIER() do { \
    asm volatile("s_waitcnt lgkmcnt(0)" ::: "memory"); \
    __builtin_amdgcn_s_barrier(); \
  } while (0)

// =====================================================================
// SINGLE-LAUNCH fused dual-stream LSTM, LAYER-SPECIALIZED waves:
// waves 0-7 = layer 0 (2 M-tiles each, read T0-T2: 3 ds_read_b128),
// waves 8-15 = layer 1 (2 M-tiles each, read T1-T4: 4 ds_read_b128).
// LDS reads/block/step 80 -> 56; per-wave MFMA = two INDEPENDENT 3-/4-chains;
// trans per SIMD unchanged (2 cells/lane). Conv (systolic) rides on the
// lighter L0 waves. Numerics identical to R5.
// =====================================================================
__global__ __launch_bounds__(1024)
__attribute__((amdgpu_waves_per_eu(4, 4)))
void fused_kernel(const float* __restrict__ xg,
                  const float* __restrict__ conv_w, const float* __restrict__ conv_b,
                  const float* __restrict__ bn_g, const float* __restrict__ bn_b,
                  const float* __restrict__ bn_m, const float* __restrict__ bn_v,
                  const float* __restrict__ cnn0_wih, const float* __restrict__ cnn0_whh,
                  const float* __restrict__ cnn0_bih, const float* __restrict__ cnn0_bhh,
                  const float* __restrict__ cnn1_wih, const float* __restrict__ cnn1_whh,
                  const float* __restrict__ cnn1_bih, const float* __restrict__ cnn1_bhh,
                  const float* __restrict__ vq0_wih, const float* __restrict__ vq0_whh,
                  const float* __restrict__ vq0_bih, const float* __restrict__ vq0_bhh,
                  const float* __restrict__ vq1_wih, const float* __restrict__ vq1_whh,
                  const float* __restrict__ vq1_bih, const float* __restrict__ vq1_bhh,
                  const float* __restrict__ proj_w, const float* __restrict__ proj_b,
                  const float* __restrict__ codebook,
                  float* __restrict__ out, float* __restrict__ ws_f,
                  int* __restrict__ ws_hist, int* __restrict__ ws_cnt)
{
  __shared__ __align__(16) _Float16 ZT[2][5][4][BT][8];  // 2 bufs x 5 K-tiles
  __shared__ __align__(16) float hfin[BT][HID];
  __shared__ __align__(16) float pbuf[BT][EDIM];
  __shared__ float xwin[4][BT][DIN];                      // x ring (CNN)

  const int tid  = threadIdx.x;
  const bool is_cnn = (blockIdx.x < NBLK_STREAM);
  const int b0   = (is_cnn ? blockIdx.x : blockIdx.x - NBLK_STREAM) * BT;
  const int w    = tid >> 6;      // wave 0..15
  const int lane = tid & 63;
  const int n16  = lane & 15;     // batch (B/D col)
  const int quad = lane >> 4;
  const bool isL1 = (w >= 8);     // layer role
  const int wm   = w & 7;         // wave index within layer group
  const int uA   = 4*wm + quad;   // unit of M-tile 0 (0..31); tile 1: uA+32

  // fold zero_ws into VQ prologues (device-scope; all 256 blocks co-resident,
  // 4096 waves << 8192 cap, 512-step loop separates prologue from epilogues)
  if (!is_cnn) {
    if (tid < NEMB) atomicExch(&ws_hist[tid], 0);
    else if (tid == NEMB) atomicExch(ws_f, 0.f);
    else if (tid == NEMB+1) atomicExch(ws_cnt, 0);
  }

  // this wave's layer weights
  const float* wih = is_cnn ? (isL1 ? cnn1_wih : cnn0_wih) : (isL1 ? vq1_wih : vq0_wih);
  const float* whh = is_cnn ? (isL1 ? cnn1_whh : cnn0_whh) : (isL1 ? vq1_whh : vq0_whh);
  const float* bih = is_cnn ? (isL1 ? cnn1_bih : cnn0_bih) : (isL1 ? vq1_bih : vq0_bih);
  const float* bhh = is_cnn ? (isL1 ? cnn1_bhh : cnn0_bhh) : (isL1 ? vq1_bhh : vq0_bhh);

  // ---- A-frags fp16, permuted rows, 2 M-tiles of ONE layer.
  // tile T rows: orow = 64*(n16&3) + 4*T + (n16>>2); unit u = 4*T + quad.
  half8 Ah[2][4];
  float bp[2][4];
#pragma unroll
  for (int mt = 0; mt < 2; ++mt) {
    const int T = wm + 8*mt;
    const int orow = 64*(n16 & 3) + 4*T + (n16 >> 2);
    if (!isL1) {
#pragma unroll
      for (int kt = 0; kt < 3; ++kt) {   // K = 96 (T0:32in-padded, T1/T2: h0)
        half8 vh;
#pragma unroll
        for (int j = 0; j < 8; ++j) {
          const int g = kt*32 + quad*8 + j;
          float wv;
          if (is_cnn) wv = (g < 32) ? wih[orow*32 + g] : whh[orow*64 + (g-32)];
          else        wv = (g < 5) ? wih[orow*5 + g] : (g < 32 ? 0.f : whh[orow*64 + (g-32)]);
          vh[j] = (_Float16)wv;
        }
        Ah[mt][kt] = vh;
      }
      Ah[mt][3] = half8{};
    } else {
#pragma unroll
      for (int kt = 0; kt < 4; ++kt) {   // K = 128 (T1..T4: h0,h1)
        half8 vh;
#pragma unroll
        for (int j = 0; j < 8; ++j) {
          const int g = kt*32 + quad*8 + j;
          float wv = (g < 64) ? wih[orow*64 + g] : whh[orow*64 + (g-64)];
          vh[j] = (_Float16)wv;
        }
        Ah[mt][kt] = vh;
      }
    }
    const int u = uA + 32*mt;
#pragma unroll
    for (int r = 0; r < 4; ++r) {
      const float k = (r == 2) ? L2E2 : L2E;
      bp[mt][r] = -k * (bih[64*r + u] + bhh[64*r + u]);
    }
  }
  const float4v zero4 = {0.f, 0.f, 0.f, 0.f};

  // conv weights (BN-folded) in registers for the 512 conv threads (L0 waves)
  float wr[16];
#pragma unroll
  for (int i = 0; i < 16; ++i) wr[i] = 0.f;
  if (is_cnn && tid < 512) {
    const int cc = tid >> 4;
    float s = bn_g[cc] * rsqrtf(bn_v[cc] + 1e-5f);
#pragma unroll
    for (int i = 0; i < 5; ++i)
#pragma unroll
      for (int tau = 0; tau < 3; ++tau)
        wr[tau*5 + i] = conv_w[cc*15 + i*3 + tau] * s;
    wr[15] = (conv_b[cc] - bn_m[cc]) * s + bn_b[cc];
  }

  // zero both Z buffers (pads + h(-1)=0)
  for (int i2 = tid; i2 < 2*5*4*BT*8/2; i2 += 1024) ((uint32_t*)ZT)[i2] = 0;

  const int xn = tid / 5, xi = tid % 5;       // x loader coords
  float xpref = 0.f;

  #define ZB(b) ((_Float16*)(&ZT[(b)][0][0][0][0]))
  #define ZIDX(tile,k32,n) (((tile)*4 + (((k32)>>3)&3))*(BT*8) + (n)*8 + ((k32)&7))

  if (is_cnn) {
    if (tid < BT*DIN) {   // x(0..3) -> ring slots 0..3
#pragma unroll
      for (int j = 0; j < 4; ++j)
        xwin[j][xn][xi] = xg[((size_t)(b0+xn)*SEQ + j)*DIN + xi];
    }
  }
  __syncthreads();   // zeroing + xwin complete before staging

  // ---- stage step-0 input: T0 of buf1 = in(0)
  if (is_cnn) {
    if (tid < 512) {   // conv y(0): taps x(-1)=0, x(0), x(1)
      const int cc = tid >> 4, cn = tid & 15;
      float s = wr[15];
#pragma unroll
      for (int i = 0; i < 5; ++i)
        s += wr[5+i]*xwin[0][cn][i] + wr[10+i]*xwin[1][cn][i];
      s = fmaxf(s, 0.f);
      ZB(1)[ZIDX(0, cc, cn)] = (_Float16)s;
    }
  } else {
    if (tid < BT*DIN) {   // x(0) -> buf1.T0
      float xv = xg[((size_t)(b0+xn)*SEQ + 0)*DIN + xi];
      ZB(1)[ZIDX(0, xi, xn)] = (_Float16)xv;
    }
  }
  __syncthreads();

  float c[2] = {0.f, 0.f};         // this wave's layer cell states (2 M-tiles)
  float h1v[2] = {0.f, 0.f};
  float convA = 0.f, convB = 0.f;  // systolic conv pipeline regs
  // MFMA G0(0) (L0 waves only) reading buf1 (T1/T2 zero = h0(-1))
  if (!isL1) {
    half8 bt0 = *(const half8*)&ZT[1][0][quad][n16][0];
    half8 bt1 = *(const half8*)&ZT[1][1][quad][n16][0];
    half8 bt2 = *(const half8*)&ZT[1][2][quad][n16][0];
#pragma unroll
    for (int mt = 0; mt < 2; ++mt) {
      float4v a0 = MFMA16(Ah[mt][0], bt0, zero4);
      a0 = MFMA16(Ah[mt][1], bt1, a0);
      a0 = MFMA16(Ah[mt][2], bt2, a0);
      float h0 = lstm_cell(a0, bp[mt], c[mt]);
      ZB(0)[ZIDX(1 + mt, uA, n16)] = (_Float16)h0;
    }
  }
  // stage y(1)/x(1) into buf0.T0; init systolic partials
  if (is_cnn) {
    if (tid < 512) {
      const int cc = tid >> 4, cn = tid & 15;
      float s = wr[15];
      float r01 = 0.f, r12 = 0.f, r02 = 0.f;
#pragma unroll
      for (int i = 0; i < 5; ++i) {
        const float x0v = xwin[0][cn][i], x1v = xwin[1][cn][i], x2v = xwin[2][cn][i];
        s   += wr[i]*x0v + wr[5+i]*x1v + wr[10+i]*x2v;   // y(1)
        r01 = fmaf(wr[i],   x1v, r01);                   // r0(x(1))
        r12 = fmaf(wr[5+i], x2v, r12);                   // r1(x(2))
        r02 = fmaf(wr[i],   x2v, r02);                   // r0(x(2))
      }
      s = fmaxf(s, 0.f);
      ZB(0)[ZIDX(0, cc, cn)] = (_Float16)s;
      convA = wr[15] + r01 + r12;     // A(0) = b + r0(1) + r1(2)
      convB = wr[15] + r02;           // B(0) = b + r0(2)
    }
    if (tid < BT*DIN) xpref = xg[((size_t)(b0+xn)*SEQ + 4)*DIN + xi];   // x(4)
  } else {
    if (tid < BT*DIN) {    // x(1) -> buf0.T0
      float xv = xg[((size_t)(b0+xn)*SEQ + 1)*DIN + xi];
      ZB(0)[ZIDX(0, xi, xn)] = (_Float16)xv;
      xpref = xg[((size_t)(b0+xn)*SEQ + 2)*DIN + xi];                   // x(2)
    }
  }
  __syncthreads();

  // ================= main loop: 1 barrier/step =================
  // Interval t: L1 waves compute G1(t) from T1-T4; L0 waves G0(t+1) from T0-T2.
#pragma unroll 2
  for (int t = 0; t < SEQ; ++t) {
    const int rb = t & 1, wrb = rb ^ 1;
    half8 btA, btB, btC, btD;
    if (isL1) {
      btA = *(const half8*)&ZT[rb][1][quad][n16][0];
      btB = *(const half8*)&ZT[rb][2][quad][n16][0];
      btC = *(const half8*)&ZT[rb][3][quad][n16][0];
      btD = *(const half8*)&ZT[rb][4][quad][n16][0];
    } else {
      btA = *(const half8*)&ZT[rb][0][quad][n16][0];
      btB = *(const half8*)&ZT[rb][1][quad][n16][0];
      btC = *(const half8*)&ZT[rb][2][quad][n16][0];
    }
    float4v a[2];
#pragma unroll
    for (int mt = 0; mt < 2; ++mt) a[mt] = MFMA16(Ah[mt][0], btA, zero4);
#pragma unroll
    for (int mt = 0; mt < 2; ++mt) a[mt] = MFMA16(Ah[mt][1], btB, a[mt]);
#pragma unroll
    for (int mt = 0; mt < 2; ++mt) a[mt] = MFMA16(Ah[mt][2], btC, a[mt]);
    if (isL1) {
#pragma unroll
      for (int mt = 0; mt < 2; ++mt) a[mt] = MFMA16(Ah[mt][3], btD, a[mt]);
    }

    __builtin_amdgcn_s_setprio(1);
    // ---- acts: 2 independent cells of this wave's layer
#pragma unroll
    for (int mt = 0; mt < 2; ++mt) {
      float h = lstm_cell(a[mt], bp[mt], c[mt]);
      ZB(wrb)[ZIDX((isL1 ? 3 : 1) + mt, uA, n16)] = (_Float16)h;
      if (isL1) {
        if (is_cnn) h1v[mt] = h;
        else if (t == SEQ-1) hfin[n16][uA + 32*mt] = h;
      }
    }
    if (is_cnn) {
      if (tid < 512) {   // systolic conv y(t+2): 5 LDS reads + 15 FMA (L0 waves)
        const float* x3 = xwin[(t+3)&3][tid & 15];
        float r0 = 0.f, r1 = 0.f, r2 = 0.f;
#pragma unroll
        for (int i = 0; i < 5; ++i) {
          const float xv = x3[i];
          r0 = fmaf(wr[i],    xv, r0);
          r1 = fmaf(wr[5+i],  xv, r1);
          r2 = fmaf(wr[10+i], xv, r2);
        }
        float y = fmaxf(convA + r2, 0.f);
        ZB(wrb)[ZIDX(0, tid >> 4, tid & 15)] = (_Float16)y;
        convA = convB + r1;          // A(t+1) = b + r0(t+2) + r1(t+3)
        convB = wr[15] + r0;         // B(t+1) = b + r0(t+3)
      }
      if (tid < BT*DIN) {
        xwin[t & 3][xn][xi] = xpref;           // commit x(t+4)
        const int tq = t + 5;
        xpref = (tq < SEQ) ? xg[((size_t)(b0+xn)*SEQ + tq)*DIN + xi] : 0.f;
      }
    } else {
      if (tid < BT*DIN) {  // x(t+2) -> buf[wrb].T0
        ZB(wrb)[ZIDX(0, xi, xn)] = (_Float16)xpref;
        const int tq = t + 3;
        xpref = (tq < SEQ) ? xg[((size_t)(b0+xn)*SEQ + tq)*DIN + xi] : 0.f;
      }
    }
    __builtin_amdgcn_s_setprio(0);
    LOOP_BARRIER();  // lgkmcnt(0) + s_barrier; global prefetch stays in flight
  }

  // ================= epilogue =================
  if (is_cnn) {
    if (isL1) {   // L1 waves hold the final h1 for units uA, uA+32
      const size_t gb = (size_t)(b0 + n16);
      out[gb*COMB + uA]             = h1v[0];
      out[OUTC + gb*COMB + uA]      = h1v[0];
      out[gb*COMB + uA + 32]        = h1v[1];
      out[OUTC + gb*COMB + uA + 32] = h1v[1];
    }
  } else {
    if (tid < 512) {  // projection: vq_proj[16][32]
      const int pn = tid >> 5, pe = tid & 31;
      float s = proj_b[pe];
      const float* pw = proj_w + pe*HID;
#pragma unroll
      for (int k = 0; k < HID; ++k) s += hfin[pn][k] * pw[k];
      pbuf[pn][pe] = s;
    }
    __syncthreads();
    // argmin: wave w handles batch w (16 waves = 16 batches), lane = code idx
    {
      const int bb = w;
      const int nn = lane;
      const float* cbn = codebook + nn*EDIM;
      float d = 0.f;
#pragma unroll
      for (int k = 0; k < EDIM; ++k) { float df = pbuf[bb][k] - cbn[k]; d += df*df; }
      int bi = nn;
#pragma unroll
      for (int off = 32; off > 0; off >>= 1) {
        float od = __shfl_down(d, off, 64);
        int   oi = __shfl_down(bi, off, 64);
        if (od < d || (od == d && oi < bi)) { d = od; bi = oi; }
      }
      bi = __shfl(bi, 0, 64);
      float lv = 0.f;
      if (nn < EDIM) {
        float q = codebook[bi*EDIM + nn];
        const size_t gb = (size_t)(b0 + bb);
        out[gb*COMB + HID + nn]        = q;
        out[OUTC + gb*COMB + HID + nn] = q;
        float df = q - pbuf[bb][nn];
        lv = df*df;
      }
#pragma unroll
      for (int off = 32; off > 0; off >>= 1) lv += __shfl_down(lv, off, 64);
      if (nn == 0) { atomicAdd(ws_f, lv); atomicAdd(&ws_hist[bi], 1); }
    }
    // ---- folded finalize: last VQ block computes loss + perplexity
    if (w == 0) {
      __threadfence();                       // release our atomics
      int cc2 = 0;
      if (lane == 0) cc2 = atomicAdd(ws_cnt, 1);
      cc2 = __shfl(cc2, 0, 64);
      if (cc2 == NBLK_STREAM - 1) {          // all 128 VQ blocks done
        __threadfence();                     // acquire
        int hv = atomicAdd(&ws_hist[lane], 0);   // coherent read
        float p = (float)hv * (1.0f / (float)B_TOT);
        float e = -p * logf(p + 1e-10f);
#pragma unroll
        for (int off = 32; off > 0; off >>= 1) e += __shfl_down(e, off, 64);
        if (lane == 0) {
          float wf = atomicAdd(ws_f, 0.0f);      // coherent read
          float mse = wf * (1.0f / (float)(B_TOT * EDIM));
          out[2*OUTC + 0] = mse * 1.01f;     // q_loss + 0.01*e_loss
          out[2*OUTC + 1] = expf(e);         // perplexity
        }
      }
    }
  }
}

extern "C" void kernel_launch(void* const* d_in, const int* in_sizes, int n_in,
                              void* d_out, int out_size, void* d_ws, size_t ws_size,
                              hipStream_t stream) {
  const float* x        = (const float*)d_in[0];
  const float* conv_w   = (const float*)d_in[1];
  const float* conv_b   = (const float*)d_in[2];
  const float* bn_g     = (const float*)d_in[3];
  const float* bn_b     = (const float*)d_in[4];
  const float* bn_m     = (const float*)d_in[5];
  const float* bn_v     = (const float*)d_in[6];
  const float* cnn0_wih = (const float*)d_in[7];
  const float* cnn0_whh = (const float*)d_in[8];
  const float* cnn0_bih = (const float*)d_in[9];
  const float* cnn0_bhh = (const float*)d_in[10];
  const float* cnn1_wih = (const float*)d_in[11];
  const float* cnn1_whh = (const float*)d_in[12];
  const float* cnn1_bih = (const float*)d_in[13];
  const float* cnn1_bhh = (const float*)d_in[14];
  const float* vq0_wih  = (const float*)d_in[15];
  const float* vq0_whh  = (const float*)d_in[16];
  const float* vq0_bih  = (const float*)d_in[17];
  const float* vq0_bhh  = (const float*)d_in[18];
  const float* vq1_wih  = (const float*)d_in[19];
  const float* vq1_whh  = (const float*)d_in[20];
  const float* vq1_bih  = (const float*)d_in[21];
  const float* vq1_bhh  = (const float*)d_in[22];
  const float* proj_w   = (const float*)d_in[23];
  const float* proj_b   = (const float*)d_in[24];
  const float* codebook = (const float*)d_in[25];

  float* out     = (float*)d_out;
  float* ws_f    = (float*)d_ws;
  int*   ws_hist = (int*)d_ws + 16;
  int*   ws_cnt  = (int*)d_ws + 88;

  hipLaunchKernelGGL(fused_kernel, dim3(2*NBLK_STREAM), dim3(1024), 0, stream,
                     x, conv_w, conv_b, bn_g, bn_b, bn_m, bn_v,
                     cnn0_wih, cnn0_whh, cnn0_bih, cnn0_bhh,
                     cnn1_wih, cnn1_whh, cnn1_bih, cnn1_bhh,
                     vq0_wih, vq0_whh, vq0_bih, vq0_bhh,
                     vq1_wih, vq1_whh, vq1_bih, vq1_bhh,
                     proj_w, proj_b, codebook, out, ws_f, ws_hist, ws_cnt);
}

// Round 7
// 517.842 us; speedup vs baseline: 1.1366x; 1.1366x over previous
//
#include <hip/hip_runtime.h>
#include <math.h>
#include <stdint.h>

#define B_TOT 2048
#define SEQ   512
#define DIN   5
#define HID   64
#define EDIM  32
#define NEMB  64
#define BT    16
#define NBLK_STREAM 128
#define COMB  96
#define OUTC  (B_TOT*COMB)

typedef __attribute__((ext_vector_type(8))) _Float16 half8;  // 8 fp16 = 4 VGPRs
typedef __attribute__((ext_vector_type(4))) float float4v;

#if __has_builtin(__builtin_amdgcn_exp2f)
#define FEXP2(x) __builtin_amdgcn_exp2f(x)
#else
#define FEXP2(x) exp2f(x)
#endif
#if __has_builtin(__builtin_amdgcn_rcpf)
#define FRCP(x) __builtin_amdgcn_rcpf(x)
#else
#define FRCP(x) (1.0f/(x))
#endif

#define L2E  1.44269504089f
#define L2E2 2.88539008178f

// 7-trans LSTM cell (5 exp2 + 2 rcp) — exact algebra, NaN-free:
//   c' = (c*Dig + (1-eg)*Df) * rcp(Dig*Df),  Dig=(1+ei)(1+eg), Df=1+ef
//   h  = (1-ec) * rcp((1+eo)(1+ec)),  ec=e^-2c' (arg clamped at 126)
__device__ __forceinline__ float lstm_cell(float4v a, const float* bp, float& c){
  float ei = FEXP2(fmaf(a[0], -L2E,  bp[0]));
  float ef = FEXP2(fmaf(a[1], -L2E,  bp[1]));
  float eg = FEXP2(fmaf(a[2], -L2E2, bp[2]));
  float eo = FEXP2(fmaf(a[3], -L2E,  bp[3]));
  float Dig = (1.f + ei) * (1.f + eg);
  float Df  = 1.f + ef;
  float rD  = FRCP(Dig * Df);
  float t   = fmaf(-eg, Df, Df);            // Df*(1-eg)
  c = fmaf(c, Dig, t) * rD;
  float ec = FEXP2(fminf(-L2E2 * c, 126.f));
  return (1.f - ec) * FRCP((1.f + eo) * (1.f + ec));
}

#define MFMA16(a,b,c) __builtin_amdgcn_mfma_f32_16x16x32_f16((a),(b),(c),0,0,0)

// In-loop barrier: drain LDS writes only; global prefetch (vmcnt) stays in
// flight across the barrier; compiler's vmcnt wait at the use covers it.
#define LOOP_BARRIER() do { \
    asm volatile("s_waitcnt lgkmcnt(0)" ::: "memory"); \
    __builtin_amdgcn_s_barrier(); \
  } while (0)

// =====================================================================
// SINGLE-LAUNCH fused dual-stream LSTM (R5 structure = measured best).
// 256 blocks x 1024 thr, 16 homogeneous waves (1 M-tile each, both layers).
// Conv systolic; xwin rows PADDED to 8 floats so the per-step window read
// is ds_read_b128 + ds_read_b32 (was 5x ds_read_b32). No setprio.
// zero_ws folded into VQ prologues; finalize folded into last VQ block.
// =====================================================================
__global__ __launch_bounds__(1024)
__attribute__((amdgpu_waves_per_eu(4, 4)))
void fused_kernel(const float* __restrict__ xg,
                  const float* __restrict__ conv_w, const float* __restrict__ conv_b,
                  const float* __restrict__ bn_g, const float* __restrict__ bn_b,
                  const float* __restrict__ bn_m, const float* __restrict__ bn_v,
                  const float* __restrict__ cnn0_wih, const float* __restrict__ cnn0_whh,
                  const float* __restrict__ cnn0_bih, const float* __restrict__ cnn0_bhh,
                  const float* __restrict__ cnn1_wih, const float* __restrict__ cnn1_whh,
                  const float* __restrict__ cnn1_bih, const float* __restrict__ cnn1_bhh,
                  const float* __restrict__ vq0_wih, const float* __restrict__ vq0_whh,
                  const float* __restrict__ vq0_bih, const float* __restrict__ vq0_bhh,
                  const float* __restrict__ vq1_wih, const float* __restrict__ vq1_whh,
                  const float* __restrict__ vq1_bih, const float* __restrict__ vq1_bhh,
                  const float* __restrict__ proj_w, const float* __restrict__ proj_b,
                  const float* __restrict__ codebook,
                  float* __restrict__ out, float* __restrict__ ws_f,
                  int* __restrict__ ws_hist, int* __restrict__ ws_cnt)
{
  __shared__ __align__(16) _Float16 ZT[2][5][4][BT][8];  // 2 bufs x 5 K-tiles
  __shared__ __align__(16) float hfin[BT][HID];
  __shared__ __align__(16) float pbuf[BT][EDIM];
  __shared__ __align__(16) float xwin[4][BT][8];          // x ring, PADDED rows

  const int tid  = threadIdx.x;
  const bool is_cnn = (blockIdx.x < NBLK_STREAM);
  const int b0   = (is_cnn ? blockIdx.x : blockIdx.x - NBLK_STREAM) * BT;
  const int w    = tid >> 6;      // wave = M-tile, 0..15
  const int lane = tid & 63;
  const int n16  = lane & 15;     // batch (B/D col)
  const int quad = lane >> 4;
  const int u    = 4*w + quad;    // unit owned by this lane

  // fold zero_ws into VQ prologues (device-scope; all 256 blocks co-resident,
  // 4096 waves << 8192 cap; 512-step loop separates prologue from epilogues)
  if (!is_cnn) {
    if (tid < NEMB) atomicExch(&ws_hist[tid], 0);
    else if (tid == NEMB) atomicExch(ws_f, 0.f);
    else if (tid == NEMB+1) atomicExch(ws_cnt, 0);
  }

  const float* wih0 = is_cnn ? cnn0_wih : vq0_wih;
  const float* whh0 = is_cnn ? cnn0_whh : vq0_whh;
  const float* bih0 = is_cnn ? cnn0_bih : vq0_bih;
  const float* bhh0 = is_cnn ? cnn0_bhh : vq0_bhh;
  const float* wih1 = is_cnn ? cnn1_wih : vq1_wih;
  const float* whh1 = is_cnn ? cnn1_whh : vq1_whh;
  const float* bih1 = is_cnn ? cnn1_bih : vq1_bih;
  const float* bhh1 = is_cnn ? cnn1_bhh : vq1_bhh;

  // ---- A-frags fp16, permuted rows. A[m=lane&15][k=quad*8+j].
  const int orow = 64*(n16 & 3) + 4*w + (n16 >> 2);
  half8 Ah0[3], Ah1[4];
#pragma unroll
  for (int kt = 0; kt < 3; ++kt) {
    half8 vh;
#pragma unroll
    for (int j = 0; j < 8; ++j) {
      const int g = kt*32 + quad*8 + j;
      float wv;
      if (is_cnn) wv = (g < 32) ? wih0[orow*32 + g] : whh0[orow*64 + (g-32)];
      else        wv = (g < 5) ? wih0[orow*5 + g] : (g < 32 ? 0.f : whh0[orow*64 + (g-32)]);
      vh[j] = (_Float16)wv;
    }
    Ah0[kt] = vh;
  }
#pragma unroll
  for (int kt = 0; kt < 4; ++kt) {
    half8 vh;
#pragma unroll
    for (int j = 0; j < 8; ++j) {
      const int g = kt*32 + quad*8 + j;
      float wv = (g < 64) ? wih1[orow*64 + g] : whh1[orow*64 + (g-64)];
      vh[j] = (_Float16)wv;
    }
    Ah1[kt] = vh;
  }

  // biases folded: bp = -k*L2E*(bih+bhh); gates 0=i 1=f 2=g(tanh,k=2) 3=o
  float bp0[4], bp1[4];
#pragma unroll
  for (int r = 0; r < 4; ++r) {
    const float k = (r == 2) ? L2E2 : L2E;
    bp0[r] = -k * (bih0[64*r + u] + bhh0[64*r + u]);
    bp1[r] = -k * (bih1[64*r + u] + bhh1[64*r + u]);
  }
  const float4v zero4 = {0.f, 0.f, 0.f, 0.f};

  // conv weights (BN-folded) in registers for the 512 conv threads
  float wr[16];
#pragma unroll
  for (int i = 0; i < 16; ++i) wr[i] = 0.f;
  if (is_cnn && tid < 512) {
    const int cc = tid >> 4;
    float s = bn_g[cc] * rsqrtf(bn_v[cc] + 1e-5f);
#pragma unroll
    for (int i = 0; i < 5; ++i)
#pragma unroll
      for (int tau = 0; tau < 3; ++tau)
        wr[tau*5 + i] = conv_w[cc*15 + i*3 + tau] * s;
    wr[15] = (conv_b[cc] - bn_m[cc]) * s + bn_b[cc];
  }

  // zero both Z buffers (pads + h(-1)=0)
  for (int i2 = tid; i2 < 2*5*4*BT*8/2; i2 += 1024) ((uint32_t*)ZT)[i2] = 0;

  const int xn = tid / 5, xi = tid % 5;       // x loader coords
  float xpref = 0.f;

  #define ZB(b) ((_Float16*)(&ZT[(b)][0][0][0][0]))
  #define ZIDX(tile,k32,n) (((tile)*4 + (((k32)>>3)&3))*(BT*8) + (n)*8 + ((k32)&7))

  if (is_cnn) {
    if (tid < BT*DIN) {   // x(0..3) -> ring slots 0..3
#pragma unroll
      for (int j = 0; j < 4; ++j)
        xwin[j][xn][xi] = xg[((size_t)(b0+xn)*SEQ + j)*DIN + xi];
    }
  }
  __syncthreads();   // zeroing + xwin complete before staging

  // ---- stage step-0 input: T0 of buf1 = in(0)
  if (is_cnn) {
    if (tid < 512) {   // conv y(0): taps x(-1)=0, x(0), x(1)
      const int cc = tid >> 4, cn = tid & 15;
      float s = wr[15];
#pragma unroll
      for (int i = 0; i < 5; ++i)
        s += wr[5+i]*xwin[0][cn][i] + wr[10+i]*xwin[1][cn][i];
      s = fmaxf(s, 0.f);
      ZB(1)[ZIDX(0, cc, cn)] = (_Float16)s;
    }
  } else {
    if (tid < BT*DIN) {   // x(0) -> buf1.T0
      float xv = xg[((size_t)(b0+xn)*SEQ + 0)*DIN + xi];
      ZB(1)[ZIDX(0, xi, xn)] = (_Float16)xv;
    }
  }
  __syncthreads();

  float c0 = 0.f, c1 = 0.f, h1v = 0.f;
  float convA = 0.f, convB = 0.f;          // systolic conv pipeline regs
  // MFMA G0(0) reading buf1 (T1/T2 zero = h0(-1))
  {
    half8 bt0 = *(const half8*)&ZT[1][0][quad][n16][0];
    half8 bt1 = *(const half8*)&ZT[1][1][quad][n16][0];
    half8 bt2 = *(const half8*)&ZT[1][2][quad][n16][0];
    float4v a0 = MFMA16(Ah0[0], bt0, zero4);
    a0 = MFMA16(Ah0[1], bt1, a0);
    a0 = MFMA16(Ah0[2], bt2, a0);
    float h0 = lstm_cell(a0, bp0, c0);
    ZB(0)[ZIDX(1 + (u>>5), u & 31, n16)] = (_Float16)h0;
  }
  // stage y(1)/x(1) into buf0.T0; init systolic partials
  if (is_cnn) {
    if (tid < 512) {
      const int cc = tid >> 4, cn = tid & 15;
      float s = wr[15];
      float r01 = 0.f, r12 = 0.f, r02 = 0.f;
#pragma unroll
      for (int i = 0; i < 5; ++i) {
        const float x0v = xwin[0][cn][i], x1v = xwin[1][cn][i], x2v = xwin[2][cn][i];
        s   += wr[i]*x0v + wr[5+i]*x1v + wr[10+i]*x2v;   // y(1)
        r01 = fmaf(wr[i],   x1v, r01);                   // r0(x(1))
        r12 = fmaf(wr[5+i], x2v, r12);                   // r1(x(2))
        r02 = fmaf(wr[i],   x2v, r02);                   // r0(x(2))
      }
      s = fmaxf(s, 0.f);
      ZB(0)[ZIDX(0, cc, cn)] = (_Float16)s;
      convA = wr[15] + r01 + r12;     // A(0) = b + r0(1) + r1(2)
      convB = wr[15] + r02;           // B(0) = b + r0(2)
    }
    if (tid < BT*DIN) xpref = xg[((size_t)(b0+xn)*SEQ + 4)*DIN + xi];   // x(4)
  } else {
    if (tid < BT*DIN) {    // x(1) -> buf0.T0
      float xv = xg[((size_t)(b0+xn)*SEQ + 1)*DIN + xi];
      ZB(0)[ZIDX(0, xi, xn)] = (_Float16)xv;
      xpref = xg[((size_t)(b0+xn)*SEQ + 2)*DIN + xi];                   // x(2)
    }
  }
  __syncthreads();

  // ================= main loop: 1 barrier/step =================
#pragma unroll 2
  for (int t = 0; t < SEQ; ++t) {
    const int rb = t & 1, wrb = rb ^ 1;
    // ---- MFMA G1(t), G0(t+1) from buf[rb]
    half8 bt0 = *(const half8*)&ZT[rb][0][quad][n16][0];
    half8 bt1 = *(const half8*)&ZT[rb][1][quad][n16][0];
    half8 bt2 = *(const half8*)&ZT[rb][2][quad][n16][0];
    half8 bt3 = *(const half8*)&ZT[rb][3][quad][n16][0];
    half8 bt4 = *(const half8*)&ZT[rb][4][quad][n16][0];
    float4v a1 = MFMA16(Ah1[0], bt1, zero4);
    a1 = MFMA16(Ah1[1], bt2, a1);
    a1 = MFMA16(Ah1[2], bt3, a1);
    a1 = MFMA16(Ah1[3], bt4, a1);
    float4v a0 = MFMA16(Ah0[0], bt0, zero4);
    a0 = MFMA16(Ah0[1], bt1, a0);
    a0 = MFMA16(Ah0[2], bt2, a0);

    // ---- acts (7-trans cells) + writes into buf[wrb]
    {
      float h1 = lstm_cell(a1, bp1, c1);
      ZB(wrb)[ZIDX(3 + (u>>5), u & 31, n16)] = (_Float16)h1;
      if (is_cnn) h1v = h1;
      else if (t == SEQ-1) hfin[n16][u] = h1;
    }
    {
      float h0 = lstm_cell(a0, bp0, c0);
      ZB(wrb)[ZIDX(1 + (u>>5), u & 31, n16)] = (_Float16)h0;
    }
    if (is_cnn) {
      if (tid < 512) {   // systolic conv y(t+2): b128+b32 LDS read + 15 FMA
        const float* x3 = &xwin[(t+3)&3][tid & 15][0];
        const float4v x4 = *(const float4v*)x3;
        const float  xlast = x3[4];
        float r0 = 0.f, r1 = 0.f, r2 = 0.f;
#pragma unroll
        for (int i = 0; i < 4; ++i) {
          r0 = fmaf(wr[i],    x4[i], r0);
          r1 = fmaf(wr[5+i],  x4[i], r1);
          r2 = fmaf(wr[10+i], x4[i], r2);
        }
        r0 = fmaf(wr[4],  xlast, r0);
        r1 = fmaf(wr[9],  xlast, r1);
        r2 = fmaf(wr[14], xlast, r2);
        float y = fmaxf(convA + r2, 0.f);
        ZB(wrb)[ZIDX(0, tid >> 4, tid & 15)] = (_Float16)y;
        convA = convB + r1;          // A(t+1) = b + r0(t+2) + r1(t+3)
        convB = wr[15] + r0;         // B(t+1) = b + r0(t+3)
      }
      if (tid < BT*DIN) {
        xwin[t & 3][xn][xi] = xpref;           // commit x(t+4)
        const int tq = t + 5;
        xpref = (tq < SEQ) ? xg[((size_t)(b0+xn)*SEQ + tq)*DIN + xi] : 0.f;
      }
    } else {
      if (tid < BT*DIN) {  // x(t+2) -> buf[wrb].T0
        ZB(wrb)[ZIDX(0, xi, xn)] = (_Float16)xpref;
        const int tq = t + 3;
        xpref = (tq < SEQ) ? xg[((size_t)(b0+xn)*SEQ + tq)*DIN + xi] : 0.f;
      }
    }
    LOOP_BARRIER();  // lgkmcnt(0) + s_barrier; global prefetch stays in flight
  }

  // ================= epilogue =================
  if (is_cnn) {
    const size_t gb = (size_t)(b0 + n16);
    out[gb*COMB + u]        = h1v;
    out[OUTC + gb*COMB + u] = h1v;
  } else {
    if (tid < 512) {  // projection: vq_proj[16][32]
      const int pn = tid >> 5, pe = tid & 31;
      float s = proj_b[pe];
      const float* pw = proj_w + pe*HID;
#pragma unroll
      for (int k = 0; k < HID; ++k) s += hfin[pn][k] * pw[k];
      pbuf[pn][pe] = s;
    }
    __syncthreads();
    // argmin: wave w handles batch w (16 waves = 16 batches), lane = code idx
    {
      const int bb = w;
      const int nn = lane;
      const float* cbn = codebook + nn*EDIM;
      float d = 0.f;
#pragma unroll
      for (int k = 0; k < EDIM; ++k) { float df = pbuf[bb][k] - cbn[k]; d += df*df; }
      int bi = nn;
#pragma unroll
      for (int off = 32; off > 0; off >>= 1) {
        float od = __shfl_down(d, off, 64);
        int   oi = __shfl_down(bi, off, 64);
        if (od < d || (od == d && oi < bi)) { d = od; bi = oi; }
      }
      bi = __shfl(bi, 0, 64);
      float lv = 0.f;
      if (nn < EDIM) {
        float q = codebook[bi*EDIM + nn];
        const size_t gb = (size_t)(b0 + bb);
        out[gb*COMB + HID + nn]        = q;
        out[OUTC + gb*COMB + HID + nn] = q;
        float df = q - pbuf[bb][nn];
        lv = df*df;
      }
#pragma unroll
      for (int off = 32; off > 0; off >>= 1) lv += __shfl_down(lv, off, 64);
      if (nn == 0) { atomicAdd(ws_f, lv); atomicAdd(&ws_hist[bi], 1); }
    }
    // ---- folded finalize: last VQ block computes loss + perplexity
    if (w == 0) {
      __threadfence();                       // release our atomics
      int cc2 = 0;
      if (lane == 0) cc2 = atomicAdd(ws_cnt, 1);
      cc2 = __shfl(cc2, 0, 64);
      if (cc2 == NBLK_STREAM - 1) {          // all 128 VQ blocks done
        __threadfence();                     // acquire
        int hv = atomicAdd(&ws_hist[lane], 0);   // coherent read
        float p = (float)hv * (1.0f / (float)B_TOT);
        float e = -p * logf(p + 1e-10f);
#pragma unroll
        for (int off = 32; off > 0; off >>= 1) e += __shfl_down(e, off, 64);
        if (lane == 0) {
          float wf = atomicAdd(ws_f, 0.0f);      // coherent read
          float mse = wf * (1.0f / (float)(B_TOT * EDIM));
          out[2*OUTC + 0] = mse * 1.01f;     // q_loss + 0.01*e_loss
          out[2*OUTC + 1] = expf(e);         // perplexity
        }
      }
    }
  }
}

extern "C" void kernel_launch(void* const* d_in, const int* in_sizes, int n_in,
                              void* d_out, int out_size, void* d_ws, size_t ws_size,
                              hipStream_t stream) {
  const float* x        = (const float*)d_in[0];
  const float* conv_w   = (const float*)d_in[1];
  const float* conv_b   = (const float*)d_in[2];
  const float* bn_g     = (const float*)d_in[3];
  const float* bn_b     = (const float*)d_in[4];
  const float* bn_m     = (const float*)d_in[5];
  const float* bn_v     = (const float*)d_in[6];
  const float* cnn0_wih = (const float*)d_in[7];
  const float* cnn0_whh = (const float*)d_in[8];
  const float* cnn0_bih = (const float*)d_in[9];
  const float* cnn0_bhh = (const float*)d_in[10];
  const float* cnn1_wih = (const float*)d_in[11];
  const float* cnn1_whh = (const float*)d_in[12];
  const float* cnn1_bih = (const float*)d_in[13];
  const float* cnn1_bhh = (const float*)d_in[14];
  const float* vq0_wih  = (const float*)d_in[15];
  const float* vq0_whh  = (const float*)d_in[16];
  const float* vq0_bih  = (const float*)d_in[17];
  const float* vq0_bhh  = (const float*)d_in[18];
  const float* vq1_wih  = (const float*)d_in[19];
  const float* vq1_whh  = (const float*)d_in[20];
  const float* vq1_bih  = (const float*)d_in[21];
  const float* vq1_bhh  = (const float*)d_in[22];
  const float* proj_w   = (const float*)d_in[23];
  const float* proj_b   = (const float*)d_in[24];
  const float* codebook = (const float*)d_in[25];

  float* out     = (float*)d_out;
  float* ws_f    = (float*)d_ws;
  int*   ws_hist = (int*)d_ws + 16;
  int*   ws_cnt  = (int*)d_ws + 88;

  hipLaunchKernelGGL(fused_kernel, dim3(2*NBLK_STREAM), dim3(1024), 0, stream,
                     x, conv_w, conv_b, bn_g, bn_b, bn_m, bn_v,
                     cnn0_wih, cnn0_whh, cnn0_bih, cnn0_bhh,
                     cnn1_wih, cnn1_whh, cnn1_bih, cnn1_bhh,
                     vq0_wih, vq0_whh, vq0_bih, vq0_bhh,
                     vq1_wih, vq1_whh, vq1_bih, vq1_bhh,
                     proj_w, proj_b, codebook, out, ws_f, ws_hist, ws_cnt);
}